// Round 14
// baseline (1019.457 us; speedup 1.0000x reference)
//
#include <hip/hip_runtime.h>
#include <hip/hip_cooperative_groups.h>

namespace cg = cooperative_groups;

#define NN 50000
#define NE 800000
#define BSHIFT 8
#define NB_BUCKET ((NN + 255) >> BSHIFT)       // 196
#define BCAP 8192                              // slots per bucket region (avg 4096)
#define EPB 2048                               // edges per binA chunk
#define NBLK_E ((NE + EPB - 1) / EPB)          // 391

#define CVT_BLKS 6250                          // NN*128/4/256 exactly
#define PREP_BLKS 32

typedef short short8 __attribute__((ext_vector_type(8)));
typedef short short4v __attribute__((ext_vector_type(4)));
typedef float f32x4 __attribute__((ext_vector_type(4)));

__device__ inline unsigned short bf16_rne(float f) {
    unsigned u = __float_as_uint(f);
    unsigned r = (u + 0x7fffu + ((u >> 16) & 1u)) >> 16;
    return (unsigned short)r;
}
__device__ inline float bf16_to_f32(unsigned short h) {
    return __uint_as_float((unsigned)h << 16);
}

struct Params {
    const float* x;
    const int* src;
    const int* dst;
    const float* W1l; const float* W1r; const float* b1;
    const float* W2l; const float* W2r; const float* b2;
    const float* Wfc; const float* bfc;
    float* out;
    int* cursor0;
    short* wf;
    unsigned* packed;
    int* row_ptr;
    float* invdeg;
    int* col;
    unsigned short* xb;
    unsigned short* h1b;
    unsigned short* aggb;
    int n; int ne;
};

// ---------------- phase devices (grid-stride; shared by mega + fallback) -----

__device__ void setup_phase(const Params& p, int tid) {
    for (int u = blockIdx.x; u < CVT_BLKS + PREP_BLKS; u += gridDim.x) {
        if (u < CVT_BLKS) {                   // x -> bf16, one float4/thread
            int i = u * 256 + tid;
            float4 v = ((const float4*)p.x)[i];
            short4v r;
            r[0] = (short)bf16_rne(v.x);
            r[1] = (short)bf16_rne(v.y);
            r[2] = (short)bf16_rne(v.z);
            r[3] = (short)bf16_rne(v.w);
            ((short4v*)p.xb)[i] = r;
        } else {                              // weight split + fragment reorder
            int t = (u - CVT_BLKS) * 256 + tid;   // 0..8191
            int mat = t >> 11;
            const float* W = (mat == 0) ? p.W1l : (mat == 1) ? p.W1r : (mat == 2) ? p.W2l : p.W2r;
            short* outw = p.wf + (size_t)mat * 32768;
            int r = t & 2047;
            int nt = r >> 8;
            int kc = (r >> 6) & 3;
            int lane = r & 63;
            int n = nt * 16 + (lane & 15);
            int kbase = kc * 32 + ((lane >> 4) << 3);
            short8 vh, vl;
#pragma unroll
            for (int j = 0; j < 8; ++j) {
                float w = W[(size_t)(kbase + j) * 128 + n];
                unsigned short h = bf16_rne(w);
                unsigned short l = bf16_rne(w - bf16_to_f32(h));
                vh[j] = (short)h;
                vl[j] = (short)l;
            }
            size_t o = ((((size_t)nt * 4 + kc) * 2) * 64 + lane) * 8;
            *(short8*)(outw + o) = vh;
            *(short8*)(outw + o + 512) = vl;
        }
    }
    if (blockIdx.x == 0 && tid < NB_BUCKET) p.cursor0[tid] = 0;
}

__device__ void binA_phase(const Params& p, int tid) {
    __shared__ int cnt[NB_BUCKET];
    __shared__ int gstart[NB_BUCKET];
    __shared__ int cur[NB_BUCKET];
    for (int chunk = blockIdx.x; chunk < NBLK_E; chunk += gridDim.x) {
        if (tid < NB_BUCKET) cnt[tid] = 0;
        __syncthreads();
        int base = chunk * EPB + tid * 8;
        int s[8], d[8];
        int m = 0;
        if (base + 8 <= p.ne) {
            *(int4*)&s[0] = *(const int4*)(p.src + base);
            *(int4*)&s[4] = *(const int4*)(p.src + base + 4);
            *(int4*)&d[0] = *(const int4*)(p.dst + base);
            *(int4*)&d[4] = *(const int4*)(p.dst + base + 4);
            m = 8;
        } else if (base < p.ne) {
            m = p.ne - base;
            for (int i = 0; i < m; ++i) { s[i] = p.src[base + i]; d[i] = p.dst[base + i]; }
        }
        for (int i = 0; i < m; ++i) atomicAdd(&cnt[d[i] >> BSHIFT], 1);
        __syncthreads();
        if (tid < NB_BUCKET) {
            gstart[tid] = tid * BCAP + atomicAdd(&p.cursor0[tid], cnt[tid]);
            cur[tid] = 0;
        }
        __syncthreads();
        for (int i = 0; i < m; ++i) {
            int b = d[i] >> BSHIFT;
            int l = atomicAdd(&cur[b], 1);
            p.packed[gstart[b] + l] = ((unsigned)(d[i] & 255) << 16) | (unsigned)s[i];
        }
        __syncthreads();
    }
}

__device__ void binB_phase(const Params& p, int tid) {
    __shared__ int sdeg[256];
    __shared__ int scur[256];
    __shared__ int sred[256];
    __shared__ int swv[4];
    int lane = tid & 63, wid = tid >> 6;
    for (int b = blockIdx.x; b < NB_BUCKET; b += gridDim.x) {
        // bucket prefix: ebeg = sum cursor0[0..b-1] via tree reduce
        sred[tid] = (tid < b) ? p.cursor0[tid] : 0;
        sdeg[tid] = 0;
        __syncthreads();
        for (int dd = 128; dd > 0; dd >>= 1) {
            if (tid < dd) sred[tid] += sred[tid + dd];
            __syncthreads();
        }
        int ebeg = sred[0];
        int cntE = p.cursor0[b];
        const unsigned* pk = p.packed + (size_t)b * BCAP;
        for (int e = tid; e < cntE; e += 256) atomicAdd(&sdeg[pk[e] >> 16], 1);
        __syncthreads();
        int v = sdeg[tid];
        int incl = v;
#pragma unroll
        for (int d = 1; d < 64; d <<= 1) {
            int u = __shfl_up(incl, d, 64);
            if (lane >= d) incl += u;
        }
        if (lane == 63) swv[wid] = incl;
        __syncthreads();
        int wbase = 0;
        for (int i = 0; i < 4; ++i) wbase += (i < wid) ? swv[i] : 0;
        int excl = wbase + incl - v;
        scur[tid] = excl;
        int node = (b << BSHIFT) + tid;
        if (node < p.n) {
            p.row_ptr[node] = ebeg + excl;
            p.invdeg[node] = 1.0f / (float)(v > 0 ? v : 1);
        }
        if (b == 0 && tid == 0) p.row_ptr[p.n] = p.ne;
        __syncthreads();
        for (int e = tid; e < cntE; e += 256) {
            unsigned w = pk[e];
            int dl = w >> 16;
            int pos = ebeg + atomicAdd(&scur[dl], 1);
            p.col[pos] = (int)(w & 0xffffu);
        }
        __syncthreads();
    }
}

// mean aggregation: grid-stride over node quads, wave per node, x4 unroll
__device__ void agg_phase(const Params& p, const unsigned short* __restrict__ hb,
                          unsigned short* __restrict__ outb, int tid) {
    int lane = tid & 63;
    int slot = lane >> 4, sub = lane & 15;
    const unsigned short* base = hb + (sub << 3);
    for (int q = blockIdx.x; q < (NN + 3) / 4; q += gridDim.x) {
        int node = q * 4 + (tid >> 6);
        if (node >= p.n) continue;            // no barrier below: safe
        int beg = p.row_ptr[node], end = p.row_ptr[node + 1];
        float acc[8];
#pragma unroll
        for (int j = 0; j < 8; ++j) acc[j] = 0.f;
        int e = beg + slot;
        for (; e + 12 < end; e += 16) {
            int j0 = p.col[e];
            int j1 = p.col[e + 4];
            int j2 = p.col[e + 8];
            int j3 = p.col[e + 12];
            uint4 v0 = *(const uint4*)(base + ((size_t)j0 << 7));
            uint4 v1 = *(const uint4*)(base + ((size_t)j1 << 7));
            uint4 v2 = *(const uint4*)(base + ((size_t)j2 << 7));
            uint4 v3 = *(const uint4*)(base + ((size_t)j3 << 7));
            unsigned w0[4] = {v0.x, v0.y, v0.z, v0.w};
            unsigned w1[4] = {v1.x, v1.y, v1.z, v1.w};
            unsigned w2[4] = {v2.x, v2.y, v2.z, v2.w};
            unsigned w3[4] = {v3.x, v3.y, v3.z, v3.w};
#pragma unroll
            for (int d = 0; d < 4; ++d) {
                acc[2 * d + 0] += __uint_as_float(w0[d] << 16);
                acc[2 * d + 1] += __uint_as_float(w0[d] & 0xffff0000u);
                acc[2 * d + 0] += __uint_as_float(w1[d] << 16);
                acc[2 * d + 1] += __uint_as_float(w1[d] & 0xffff0000u);
                acc[2 * d + 0] += __uint_as_float(w2[d] << 16);
                acc[2 * d + 1] += __uint_as_float(w2[d] & 0xffff0000u);
                acc[2 * d + 0] += __uint_as_float(w3[d] << 16);
                acc[2 * d + 1] += __uint_as_float(w3[d] & 0xffff0000u);
            }
        }
        for (; e < end; e += 4) {
            int j0 = p.col[e];
            uint4 v0 = *(const uint4*)(base + ((size_t)j0 << 7));
            unsigned w0[4] = {v0.x, v0.y, v0.z, v0.w};
#pragma unroll
            for (int d = 0; d < 4; ++d) {
                acc[2 * d + 0] += __uint_as_float(w0[d] << 16);
                acc[2 * d + 1] += __uint_as_float(w0[d] & 0xffff0000u);
            }
        }
#pragma unroll
        for (int j = 0; j < 8; ++j) {
            acc[j] += __shfl_xor(acc[j], 16, 64);
            acc[j] += __shfl_xor(acc[j], 32, 64);
        }
        if (slot == 0) {
            float s = p.invdeg[node];
            short8 o;
#pragma unroll
            for (int j = 0; j < 8; ++j) o[j] = (short)bf16_rne(acc[j] * s);
            *(short8*)(outb + ((size_t)node << 7) + (sub << 3)) = o;
        }
    }
}

// dual GEMM, swapped-operand MFMA (W as A, features as B); optional fused FC
__device__ void gemm_phase(const Params& p, const unsigned short* __restrict__ A0b,
                           const unsigned short* __restrict__ A1b,
                           const short* __restrict__ Wf0, const short* __restrict__ Wf1,
                           const float* __restrict__ bias,
                           unsigned short* __restrict__ outb, int do_fc, int tid) {
    int lane = tid & 63;
    int wave = tid >> 6;
    int quad = lane >> 4, m16 = lane & 15;
    for (int tile = blockIdx.x; tile < (NN + 63) / 64; tile += gridDim.x) {
        int row_base = tile * 64 + wave * 16;
        int arow = row_base + m16;
        if (arow > p.n - 1) arow = p.n - 1;

        f32x4 acc[8];
#pragma unroll
        for (int nt = 0; nt < 8; ++nt) acc[nt] = (f32x4){0.f, 0.f, 0.f, 0.f};

        const unsigned short* ap0 = A0b + ((size_t)arow << 7) + (quad << 3);
        const unsigned short* ap1 = A1b + ((size_t)arow << 7) + (quad << 3);
#pragma unroll
        for (int kc = 0; kc < 4; ++kc) {
            short8 a0 = *(const short8*)(ap0 + kc * 32);
            short8 a1 = *(const short8*)(ap1 + kc * 32);
            const short* wp0 = Wf0 + ((size_t)kc * 2 * 64 + lane) * 8;
            const short* wp1 = Wf1 + ((size_t)kc * 2 * 64 + lane) * 8;
#pragma unroll
            for (int nt = 0; nt < 8; ++nt) {
                short8 bh0 = *(const short8*)(wp0 + (size_t)nt * 4096);
                short8 bl0 = *(const short8*)(wp0 + (size_t)nt * 4096 + 512);
                short8 bh1 = *(const short8*)(wp1 + (size_t)nt * 4096);
                short8 bl1 = *(const short8*)(wp1 + (size_t)nt * 4096 + 512);
                acc[nt] = __builtin_amdgcn_mfma_f32_16x16x32_bf16(bh0, a0, acc[nt], 0, 0, 0);
                acc[nt] = __builtin_amdgcn_mfma_f32_16x16x32_bf16(bl0, a0, acc[nt], 0, 0, 0);
                acc[nt] = __builtin_amdgcn_mfma_f32_16x16x32_bf16(bh1, a1, acc[nt], 0, 0, 0);
                acc[nt] = __builtin_amdgcn_mfma_f32_16x16x32_bf16(bl1, a1, acc[nt], 0, 0, 0);
            }
        }

        int onode = row_base + m16;
        if (!do_fc) {
            if (onode < p.n) {
                unsigned short* op = outb + ((size_t)onode << 7) + (quad << 2);
#pragma unroll
                for (int nt = 0; nt < 8; ++nt) {
                    float4 bs = *(const float4*)(bias + nt * 16 + (quad << 2));
                    short4v o;
                    o[0] = (short)bf16_rne(fmaxf(acc[nt][0] + bs.x, 0.f));
                    o[1] = (short)bf16_rne(fmaxf(acc[nt][1] + bs.y, 0.f));
                    o[2] = (short)bf16_rne(fmaxf(acc[nt][2] + bs.z, 0.f));
                    o[3] = (short)bf16_rne(fmaxf(acc[nt][3] + bs.w, 0.f));
                    *(short4v*)(op + nt * 16) = o;
                }
            }
        } else {
            float p0 = 0.f, p1 = 0.f;
#pragma unroll
            for (int nt = 0; nt < 8; ++nt) {
                float4 bs = *(const float4*)(bias + nt * 16 + (quad << 2));
                float bv[4] = {bs.x, bs.y, bs.z, bs.w};
#pragma unroll
                for (int r = 0; r < 4; ++r) {
                    float v = fmaxf(acc[nt][r] + bv[r], 0.f);
                    int hid = nt * 16 + (quad << 2) + r;
                    float2 wv = *(const float2*)(p.Wfc + 2 * hid);
                    p0 += v * wv.x;
                    p1 += v * wv.y;
                }
            }
            p0 += __shfl_xor(p0, 16, 64);
            p0 += __shfl_xor(p0, 32, 64);
            p1 += __shfl_xor(p1, 16, 64);
            p1 += __shfl_xor(p1, 32, 64);
            if (quad == 0 && onode < p.n) {
                float2 o;
                o.x = p0 + p.bfc[0];
                o.y = p1 + p.bfc[1];
                *(float2*)(p.out + 2 * (size_t)onode) = o;
            }
        }
    }
}

// ---------------- cooperative mega-kernel ----------------
__global__ __launch_bounds__(256, 4) void mega_kernel(Params p) {
    cg::grid_group grid = cg::this_grid();
    int tid = threadIdx.x;

    setup_phase(p, tid);
    grid.sync();
    binA_phase(p, tid);
    grid.sync();
    binB_phase(p, tid);
    grid.sync();
    agg_phase(p, p.xb, p.aggb, tid);
    grid.sync();
    gemm_phase(p, p.aggb, p.xb, p.wf, p.wf + 32768, p.b1, p.h1b, 0, tid);
    grid.sync();
    agg_phase(p, p.h1b, p.aggb, tid);
    grid.sync();
    gemm_phase(p, p.aggb, p.h1b, p.wf + 2 * 32768, p.wf + 3 * 32768, p.b2,
               (unsigned short*)0, 1, tid);
}

// ---------------- fallback wrappers (same phase code, 7 dispatches) ----------
__global__ __launch_bounds__(256, 4) void setup_wrap(Params p) { setup_phase(p, threadIdx.x); }
__global__ __launch_bounds__(256, 4) void binA_wrap(Params p)  { binA_phase(p, threadIdx.x); }
__global__ __launch_bounds__(256, 4) void binB_wrap(Params p)  { binB_phase(p, threadIdx.x); }
__global__ __launch_bounds__(256, 4) void agg_wrap(Params p, int layer) {
    if (layer == 0) agg_phase(p, p.xb, p.aggb, threadIdx.x);
    else            agg_phase(p, p.h1b, p.aggb, threadIdx.x);
}
__global__ __launch_bounds__(256, 4) void gemm_wrap(Params p, int layer) {
    if (layer == 0) gemm_phase(p, p.aggb, p.xb, p.wf, p.wf + 32768, p.b1, p.h1b, 0, threadIdx.x);
    else gemm_phase(p, p.aggb, p.h1b, p.wf + 2 * 32768, p.wf + 3 * 32768, p.b2,
                    (unsigned short*)0, 1, threadIdx.x);
}

extern "C" void kernel_launch(void* const* d_in, const int* in_sizes, int n_in,
                              void* d_out, int out_size, void* d_ws, size_t ws_size,
                              hipStream_t stream) {
    const float* x   = (const float*)d_in[0];
    const int* edge  = (const int*)d_in[1];

    char* ws = (char*)d_ws;
    size_t off = 0;
    auto alloc = [&](size_t bytes) -> char* {
        char* p = ws + off;
        off = (off + bytes + 511) & ~(size_t)511;
        return p;
    };

    Params p;
    p.x   = x;
    p.src = edge;
    p.dst = edge + NE;
    p.W1l = (const float*)d_in[2];
    p.W1r = (const float*)d_in[3];
    p.b1  = (const float*)d_in[4];
    p.W2l = (const float*)d_in[5];
    p.W2r = (const float*)d_in[6];
    p.b2  = (const float*)d_in[7];
    p.Wfc = (const float*)d_in[8];
    p.bfc = (const float*)d_in[9];
    p.out = (float*)d_out;
    p.row_ptr = (int*)alloc((size_t)(NN + 1) * 4);
    p.invdeg  = (float*)alloc((size_t)NN * 4);
    p.cursor0 = (int*)alloc((size_t)NB_BUCKET * 4);
    p.wf      = (short*)alloc((size_t)4 * 32768 * 2);
    p.packed  = (unsigned*)alloc((size_t)NB_BUCKET * BCAP * 4);
    p.col     = (int*)alloc((size_t)NE * 4);
    p.aggb    = (unsigned short*)alloc((size_t)NN * 128 * 2);
    p.xb      = (unsigned short*)alloc((size_t)NN * 128 * 2);
    p.h1b     = (unsigned short*)alloc((size_t)NN * 128 * 2);
    p.n = NN;
    p.ne = NE;
    (void)ws_size; (void)in_sizes; (void)n_in; (void)out_size;

    // occupancy-derived cooperative grid; checked launch with deterministic fallback
    int blocksPerCU = 0;
    hipError_t qerr = hipOccupancyMaxActiveBlocksPerMultiprocessor(&blocksPerCU, mega_kernel, 256, 0);
    int gridB = (qerr == hipSuccess) ? blocksPerCU * 256 : 0;
    if (gridB > 1024) gridB = 1024;

    hipError_t lerr = hipErrorUnknown;
    if (gridB >= 128) {
        void* args[] = {&p};
        lerr = hipLaunchCooperativeKernel((const void*)mega_kernel, dim3(gridB), dim3(256),
                                          args, 0, stream);
    }
    if (lerr != hipSuccess) {
        (void)hipGetLastError();   // clear sticky error from the failed launch
        setup_wrap<<<CVT_BLKS + PREP_BLKS, 256, 0, stream>>>(p);
        binA_wrap<<<NBLK_E, 256, 0, stream>>>(p);
        binB_wrap<<<NB_BUCKET, 256, 0, stream>>>(p);
        agg_wrap<<<(NN + 3) / 4, 256, 0, stream>>>(p, 0);
        gemm_wrap<<<(NN + 63) / 64, 256, 0, stream>>>(p, 0);
        agg_wrap<<<(NN + 3) / 4, 256, 0, stream>>>(p, 1);
        gemm_wrap<<<(NN + 63) / 64, 256, 0, stream>>>(p, 1);
    }
}

// Round 15
// 317.709 us; speedup vs baseline: 3.2088x; 3.2088x over previous
//
#include <hip/hip_runtime.h>

#define NN 50000
#define NE 800000
#define BSHIFT 9
#define NB_BUCKET ((NN + 511) >> BSHIFT)       // 98
#define BCAP 16384                             // slots per bucket region
#define EPB 2048                               // edges per binA block
#define NBLK_E ((NE + EPB - 1) / EPB)          // 391

// setup kernel block partition
#define CVT_BLKS 6250                          // NN*128/4/256 exactly
#define PREP_BLKS 32
#define SETUP_GRID (CVT_BLKS + PREP_BLKS + 1)

#define AGG_GRID 8192                          // 4 slices x 2048 node-group strides

typedef short short8 __attribute__((ext_vector_type(8)));
typedef short short4v __attribute__((ext_vector_type(4)));
typedef float f32x4 __attribute__((ext_vector_type(4)));

__device__ inline unsigned short bf16_rne(float f) {
    unsigned u = __float_as_uint(f);
    unsigned r = (u + 0x7fffu + ((u >> 16) & 1u)) >> 16;
    return (unsigned short)r;
}
__device__ inline float bf16_to_f32(unsigned short h) {
    return __uint_as_float((unsigned)h << 16);
}

// ---- fused setup: cvt x->bf16 | weight prep | zero bucket cursors ----------
__global__ __launch_bounds__(256) void setup_kernel(const float* __restrict__ x,
                                                    unsigned short* __restrict__ xb,
                                                    const float* __restrict__ W0,
                                                    const float* __restrict__ W1,
                                                    const float* __restrict__ W2,
                                                    const float* __restrict__ W3,
                                                    short* __restrict__ wf,
                                                    int* __restrict__ cursor0) {
    int b = blockIdx.x;
    if (b < CVT_BLKS) {                       // x -> bf16 (one float4/thread, exact)
        int i = b * 256 + threadIdx.x;
        float4 v = ((const float4*)x)[i];
        short4v r;
        r[0] = (short)bf16_rne(v.x);
        r[1] = (short)bf16_rne(v.y);
        r[2] = (short)bf16_rne(v.z);
        r[3] = (short)bf16_rne(v.w);
        ((short4v*)xb)[i] = r;
    } else if (b < CVT_BLKS + PREP_BLKS) {    // weight split+fragment reorder
        int t = (b - CVT_BLKS) * 256 + threadIdx.x;   // 0..8191
        int mat = t >> 11;
        const float* W = (mat == 0) ? W0 : (mat == 1) ? W1 : (mat == 2) ? W2 : W3;
        short* out = wf + (size_t)mat * 32768;
        int r = t & 2047;
        int nt = r >> 8;
        int kc = (r >> 6) & 3;
        int lane = r & 63;
        int n = nt * 16 + (lane & 15);
        int kbase = kc * 32 + ((lane >> 4) << 3);
        short8 vh, vl;
#pragma unroll
        for (int j = 0; j < 8; ++j) {
            float w = W[(size_t)(kbase + j) * 128 + n];
            unsigned short h = bf16_rne(w);
            unsigned short l = bf16_rne(w - bf16_to_f32(h));
            vh[j] = (short)h;
            vl[j] = (short)l;
        }
        size_t o = ((((size_t)nt * 4 + kc) * 2) * 64 + lane) * 8;
        *(short8*)(out + o) = vh;
        *(short8*)(out + o + 512) = vl;
    } else {                                  // zero bucket cursors
        if (threadIdx.x < NB_BUCKET) cursor0[threadIdx.x] = 0;
    }
}

// ---- phase A: bin edges into fixed bucket regions, packed (dl<<16)|src -----
__global__ __launch_bounds__(256) void binA_kernel(const int* __restrict__ src,
                                                   const int* __restrict__ dst,
                                                   int* __restrict__ cursor0,
                                                   unsigned* __restrict__ packed, int ne) {
    __shared__ int cnt[NB_BUCKET];
    __shared__ int gstart[NB_BUCKET];
    __shared__ int cur[NB_BUCKET];
    int t = threadIdx.x;
    if (t < NB_BUCKET) cnt[t] = 0;
    __syncthreads();
    int base = blockIdx.x * EPB + t * 8;
    int s[8], d[8];
    int m = 0;
    if (base + 8 <= ne) {
        *(int4*)&s[0] = *(const int4*)(src + base);
        *(int4*)&s[4] = *(const int4*)(src + base + 4);
        *(int4*)&d[0] = *(const int4*)(dst + base);
        *(int4*)&d[4] = *(const int4*)(dst + base + 4);
        m = 8;
    } else if (base < ne) {
        m = ne - base;
        for (int i = 0; i < m; ++i) { s[i] = src[base + i]; d[i] = dst[base + i]; }
    }
    for (int i = 0; i < m; ++i) atomicAdd(&cnt[d[i] >> BSHIFT], 1);
    __syncthreads();
    if (t < NB_BUCKET) {
        gstart[t] = t * BCAP + atomicAdd(&cursor0[t], cnt[t]);
        cur[t] = 0;
    }
    __syncthreads();
    for (int i = 0; i < m; ++i) {
        int b = d[i] >> BSHIFT;
        int l = atomicAdd(&cur[b], 1);
        packed[gstart[b] + l] = ((unsigned)(d[i] & 511) << 16) | (unsigned)s[i];
    }
}

// ---- phase B: one block per bucket; LDS deg + wave-scan -> row_ptr/col -----
__global__ __launch_bounds__(512) void binB_kernel(const unsigned* __restrict__ packed,
                                                   const int* __restrict__ cursor0,
                                                   int* __restrict__ row_ptr,
                                                   float* __restrict__ inv_deg,
                                                   int* __restrict__ col, int n, int ne) {
    __shared__ int sdeg[512];
    __shared__ int scur[512];
    __shared__ int scnt[NB_BUCKET];
    __shared__ int sebeg[NB_BUCKET];
    __shared__ int swv[8];
    int b = blockIdx.x, t = threadIdx.x;
    int lane = t & 63, wid = t >> 6;
    if (t < NB_BUCKET) scnt[t] = cursor0[t];
    sdeg[t] = 0;
    __syncthreads();
    if (t == 0) {                 // serial 98-scan (cheap, per-block)
        int run = 0;
        for (int i = 0; i < NB_BUCKET; ++i) { sebeg[i] = run; run += scnt[i]; }
    }
    __syncthreads();
    int ebeg = sebeg[b];
    int cntE = scnt[b];
    const unsigned* pk = packed + (size_t)b * BCAP;
    for (int e = t; e < cntE; e += 512) atomicAdd(&sdeg[pk[e] >> 16], 1);
    __syncthreads();
    int v = sdeg[t];
    int incl = v;                 // wave-level inclusive scan
#pragma unroll
    for (int d = 1; d < 64; d <<= 1) {
        int u = __shfl_up(incl, d, 64);
        if (lane >= d) incl += u;
    }
    if (lane == 63) swv[wid] = incl;
    __syncthreads();
    int wbase = 0;
    for (int i = 0; i < 8; ++i) wbase += (i < wid) ? swv[i] : 0;
    int excl = wbase + incl - v;
    scur[t] = excl;
    int node = (b << BSHIFT) + t;
    if (node < n) {
        row_ptr[node] = ebeg + excl;
        inv_deg[node] = 1.0f / (float)(v > 0 ? v : 1);
    }
    if (b == 0 && t == 0) row_ptr[n] = ne;
    __syncthreads();
    for (int e = t; e < cntE; e += 512) {
        unsigned w = pk[e];
        int dl = w >> 16;
        int pos = ebeg + atomicAdd(&scur[dl], 1);
        col[pos] = (int)(w & 0xffffu);
    }
}

// ---- mean aggregation, XCD-affine 64B feature slices -----------------------
// slice = blockIdx&3 selects one 64B cache line of each 256B feature row; with
// the blockIdx%8 -> XCD round-robin, slice s lives on XCDs {s, s+4}, whose L2
// then holds a 3.2MB column-slice (fits 4MB) -> gather served from L2, not L3.
// Wave per node-slice: eslot=lane>>4 (4 edges/round, x4 unroll = 16 in
// flight), dw=lane&15 (one dword of the slice). Line-exact slices -> no
// cross-XCD write sharing of output lines.
__global__ __launch_bounds__(256) void agg_kernel(const unsigned short* __restrict__ hb,
                                                  const int* __restrict__ row_ptr,
                                                  const int* __restrict__ col,
                                                  const float* __restrict__ inv_deg,
                                                  unsigned short* __restrict__ outb, int n) {
    int slice = blockIdx.x & 3;
    int wave = threadIdx.x >> 6, lane = threadIdx.x & 63;
    int eslot = lane >> 4, dw = lane & 15;
    const unsigned* hd = (const unsigned*)hb + (slice << 4) + dw;   // row stride 64 dwords
    int ngrp = (n + 3) >> 2;
    for (int g = blockIdx.x >> 2; g < ngrp; g += (AGG_GRID >> 2)) {
        int node = g * 4 + wave;
        if (node >= n) continue;
        int beg = row_ptr[node], end = row_ptr[node + 1];
        float a0 = 0.f, a1 = 0.f;
        int e = beg + eslot;
        for (; e + 12 < end; e += 16) {
            int j0 = col[e];
            int j1 = col[e + 4];
            int j2 = col[e + 8];
            int j3 = col[e + 12];
            unsigned v0 = hd[(size_t)j0 << 6];
            unsigned v1 = hd[(size_t)j1 << 6];
            unsigned v2 = hd[(size_t)j2 << 6];
            unsigned v3 = hd[(size_t)j3 << 6];
            a0 += __uint_as_float(v0 << 16);
            a1 += __uint_as_float(v0 & 0xffff0000u);
            a0 += __uint_as_float(v1 << 16);
            a1 += __uint_as_float(v1 & 0xffff0000u);
            a0 += __uint_as_float(v2 << 16);
            a1 += __uint_as_float(v2 & 0xffff0000u);
            a0 += __uint_as_float(v3 << 16);
            a1 += __uint_as_float(v3 & 0xffff0000u);
        }
        for (; e < end; e += 4) {
            unsigned v0 = hd[(size_t)col[e] << 6];
            a0 += __uint_as_float(v0 << 16);
            a1 += __uint_as_float(v0 & 0xffff0000u);
        }
        // reduce across the 4 eslots (lane bits 4,5)
        a0 += __shfl_xor(a0, 16, 64);
        a0 += __shfl_xor(a0, 32, 64);
        a1 += __shfl_xor(a1, 16, 64);
        a1 += __shfl_xor(a1, 32, 64);
        if (eslot == 0) {
            float s = inv_deg[node];
            unsigned short h0 = bf16_rne(a0 * s);
            unsigned short h1 = bf16_rne(a1 * s);
            ((unsigned*)outb)[((size_t)node << 6) + (slice << 4) + dw] =
                (unsigned)h0 | ((unsigned)h1 << 16);
        }
    }
}

// ---- dual GEMM, swapped-operand MFMA (W as A, features as B) (+opt FC) -----
__global__ __launch_bounds__(256) void gemm_mfma(const unsigned short* __restrict__ A0b,
                                                 const unsigned short* __restrict__ A1b,
                                                 const short* __restrict__ Wf0,
                                                 const short* __restrict__ Wf1,
                                                 const float* __restrict__ bias,
                                                 unsigned short* __restrict__ outb,
                                                 const float* __restrict__ Wfc,
                                                 const float* __restrict__ bfc,
                                                 float* __restrict__ fcout,
                                                 int n) {
    int lane = threadIdx.x & 63;
    int wave = threadIdx.x >> 6;
    int quad = lane >> 4, m16 = lane & 15;
    int row_base = blockIdx.x * 64 + wave * 16;
    int arow = row_base + m16;
    if (arow > n - 1) arow = n - 1;            // clamp (padding rows never stored)

    f32x4 acc[8];
#pragma unroll
    for (int nt = 0; nt < 8; ++nt) acc[nt] = (f32x4){0.f, 0.f, 0.f, 0.f};

    const unsigned short* ap0 = A0b + ((size_t)arow << 7) + (quad << 3);
    const unsigned short* ap1 = A1b + ((size_t)arow << 7) + (quad << 3);
#pragma unroll
    for (int kc = 0; kc < 4; ++kc) {
        short8 a0 = *(const short8*)(ap0 + kc * 32);
        short8 a1 = *(const short8*)(ap1 + kc * 32);
        const short* wp0 = Wf0 + ((size_t)kc * 2 * 64 + lane) * 8;
        const short* wp1 = Wf1 + ((size_t)kc * 2 * 64 + lane) * 8;
#pragma unroll
        for (int nt = 0; nt < 8; ++nt) {
            short8 bh0 = *(const short8*)(wp0 + (size_t)nt * 4096);
            short8 bl0 = *(const short8*)(wp0 + (size_t)nt * 4096 + 512);
            short8 bh1 = *(const short8*)(wp1 + (size_t)nt * 4096);
            short8 bl1 = *(const short8*)(wp1 + (size_t)nt * 4096 + 512);
            acc[nt] = __builtin_amdgcn_mfma_f32_16x16x32_bf16(bh0, a0, acc[nt], 0, 0, 0);
            acc[nt] = __builtin_amdgcn_mfma_f32_16x16x32_bf16(bl0, a0, acc[nt], 0, 0, 0);
            acc[nt] = __builtin_amdgcn_mfma_f32_16x16x32_bf16(bh1, a1, acc[nt], 0, 0, 0);
            acc[nt] = __builtin_amdgcn_mfma_f32_16x16x32_bf16(bl1, a1, acc[nt], 0, 0, 0);
        }
    }

    // epilogue: lane owns node (row_base+m16), hids nt*16 + quad*4 + (0..3)
    int onode = row_base + m16;
    if (outb) {
        if (onode < n) {
            unsigned short* op = outb + ((size_t)onode << 7) + (quad << 2);
#pragma unroll
            for (int nt = 0; nt < 8; ++nt) {
                float4 bs = *(const float4*)(bias + nt * 16 + (quad << 2));
                short4v o;
                o[0] = (short)bf16_rne(fmaxf(acc[nt][0] + bs.x, 0.f));
                o[1] = (short)bf16_rne(fmaxf(acc[nt][1] + bs.y, 0.f));
                o[2] = (short)bf16_rne(fmaxf(acc[nt][2] + bs.z, 0.f));
                o[3] = (short)bf16_rne(fmaxf(acc[nt][3] + bs.w, 0.f));
                *(short4v*)(op + nt * 16) = o;
            }
        }
    } else {
        // fused FC: lane holds 32 hids of its node; reduce over 4 quad groups
        float p0 = 0.f, p1 = 0.f;
#pragma unroll
        for (int nt = 0; nt < 8; ++nt) {
            float4 bs = *(const float4*)(bias + nt * 16 + (quad << 2));
            float bv[4] = {bs.x, bs.y, bs.z, bs.w};
#pragma unroll
            for (int r = 0; r < 4; ++r) {
                float v = fmaxf(acc[nt][r] + bv[r], 0.f);
                int hid = nt * 16 + (quad << 2) + r;
                float2 wv = *(const float2*)(Wfc + 2 * hid);
                p0 += v * wv.x;
                p1 += v * wv.y;
            }
        }
        p0 += __shfl_xor(p0, 16, 64);
        p0 += __shfl_xor(p0, 32, 64);
        p1 += __shfl_xor(p1, 16, 64);
        p1 += __shfl_xor(p1, 32, 64);
        if (quad == 0 && onode < n) {
            float2 o;
            o.x = p0 + bfc[0];
            o.y = p1 + bfc[1];
            *(float2*)(fcout + 2 * (size_t)onode) = o;
        }
    }
}

extern "C" void kernel_launch(void* const* d_in, const int* in_sizes, int n_in,
                              void* d_out, int out_size, void* d_ws, size_t ws_size,
                              hipStream_t stream) {
    const float* x   = (const float*)d_in[0];
    const int* edge  = (const int*)d_in[1];
    const float* W1l = (const float*)d_in[2];
    const float* W1r = (const float*)d_in[3];
    const float* b1  = (const float*)d_in[4];
    const float* W2l = (const float*)d_in[5];
    const float* W2r = (const float*)d_in[6];
    const float* b2  = (const float*)d_in[7];
    const float* Wfc = (const float*)d_in[8];
    const float* bfc = (const float*)d_in[9];
    float* out = (float*)d_out;

    const int n = NN, ne = NE;
    const int* src = edge;        // edge_index[0]
    const int* dst = edge + ne;   // edge_index[1]

    char* ws = (char*)d_ws;
    size_t off = 0;
    auto alloc = [&](size_t bytes) -> char* {
        char* p = ws + off;
        off = (off + bytes + 511) & ~(size_t)511;
        return p;
    };
    int* row_ptr     = (int*)alloc((size_t)(n + 1) * 4);
    float* invdeg    = (float*)alloc((size_t)n * 4);
    int* cursor0     = (int*)alloc((size_t)NB_BUCKET * 4);
    short* wf        = (short*)alloc((size_t)4 * 32768 * 2);
    unsigned* packed = (unsigned*)alloc((size_t)NB_BUCKET * BCAP * 4);
    int* col         = (int*)alloc((size_t)ne * 4);
    unsigned short* aggb = (unsigned short*)alloc((size_t)n * 128 * 2);
    unsigned short* xb   = (unsigned short*)alloc((size_t)n * 128 * 2);
    unsigned short* h1b  = (unsigned short*)alloc((size_t)n * 128 * 2);
    (void)ws_size; (void)in_sizes; (void)n_in; (void)out_size;

    setup_kernel<<<SETUP_GRID, 256, 0, stream>>>(x, xb, W1l, W1r, W2l, W2r, wf, cursor0);
    binA_kernel<<<NBLK_E, 256, 0, stream>>>(src, dst, cursor0, packed, ne);
    binB_kernel<<<NB_BUCKET, 512, 0, stream>>>(packed, cursor0, row_ptr, invdeg, col, n, ne);

    agg_kernel<<<AGG_GRID, 256, 0, stream>>>(xb, row_ptr, col, invdeg, aggb, n);
    gemm_mfma<<<(n + 63) / 64, 256, 0, stream>>>(aggb, xb, wf, wf + 32768, b1, h1b,
                                                 (const float*)0, (const float*)0, (float*)0, n);
    agg_kernel<<<AGG_GRID, 256, 0, stream>>>(h1b, row_ptr, col, invdeg, aggb, n);
    gemm_mfma<<<(n + 63) / 64, 256, 0, stream>>>(aggb, h1b, wf + 2 * 32768, wf + 3 * 32768, b2,
                                                 (unsigned short*)0, Wfc, bfc, out, n);
}